// Round 11
// baseline (128.260 us; speedup 1.0000x reference)
//
#include <hip/hip_runtime.h>
#include <stdint.h>

// Problem constants (fixed by setup_inputs)
#define NB 32
#define NCH 128
#define NH 56
#define NW 56
#define NHW_ 3136
#define NPIX 100352
#define PADD 58                               // padded spatial dim (h,w in [-1,56])
#define IMG_BYTES ((size_t)PADD * PADD * NCH)   // 430592
#define NTILE 17                              // 192-pixel tiles per image
#define TPX 192
#define NSLOT (NB * NTILE * 2)                // 1088 stat slots per channel
#define LROWS 7                               // staged padded rows (max span 5 + 2)
#define ROWB (PADD * NCH)                     // 7424 B per padded row

typedef int v4i __attribute__((ext_vector_type(4)));
typedef int v16i __attribute__((ext_vector_type(16)));

// ---------------------------------------------------------------------------
// 32-lane-half sum via DPP (VALU pipe). lane31 = sum(0..31), lane63 = sum(32..63).
// ---------------------------------------------------------------------------
__device__ __forceinline__ int sum32(int v) {
    v += __builtin_amdgcn_update_dpp(0, v, 0x111, 0xF, 0xF, true);  // row_shr:1
    v += __builtin_amdgcn_update_dpp(0, v, 0x112, 0xF, 0xF, true);  // row_shr:2
    v += __builtin_amdgcn_update_dpp(0, v, 0x114, 0xF, 0xF, true);  // row_shr:4
    v += __builtin_amdgcn_update_dpp(0, v, 0x118, 0xF, 0xF, true);  // row_shr:8
    v += __builtin_amdgcn_update_dpp(0, v, 0x142, 0xF, 0xF, true);  // row_bcast:15
    return v;
}

// ---------------------------------------------------------------------------
// K1: x (NCHW f32) -> act8 (padded NHWC i8 sign +1/-1). Grid covers the FULL
// padded grid; border threads write zeros (replaces the 13.8MB memset).
// ---------------------------------------------------------------------------
__global__ __launch_bounds__(256) void pack_act8(const float* __restrict__ x,
                                                 const float* __restrict__ bias0,
                                                 char* __restrict__ act8) {
    int q = blockIdx.x * 256 + threadIdx.x;
    if (q >= NB * PADD * PADD) return;
    int n = q / (PADD * PADD);
    int rem = q - n * (PADD * PADD);
    int hp = rem / PADD, wp = rem - (rem / PADD) * PADD;
    char* dst = act8 + (size_t)n * IMG_BYTES + (size_t)rem * NCH;
    if (hp == 0 || hp == PADD - 1 || wp == 0 || wp == PADD - 1) {
        v4i z = {0, 0, 0, 0};
#pragma unroll
        for (int g = 0; g < 8; ++g) *reinterpret_cast<v4i*>(dst + g * 16) = z;
        return;
    }
    int pix = (hp - 1) * NW + (wp - 1);
    const float* xb = x + (size_t)n * NCH * NHW_ + pix;
#pragma unroll
    for (int g = 0; g < 8; ++g) {
        int d[4];
#pragma unroll
        for (int dw = 0; dw < 4; ++dw) {
            unsigned v = 0;
#pragma unroll
            for (int b = 0; b < 4; ++b) {
                int c = g * 16 + dw * 4 + b;
                bool pos = (xb[(size_t)c * NHW_] + bias0[c]) > 0.f;
                v |= (unsigned)(pos ? 0x01u : 0xFFu) << (8 * b);
            }
            d[dw] = (int)v;
        }
        v4i qv = {d[0], d[1], d[2], d[3]};
        *reinterpret_cast<v4i*>(dst + g * 16) = qv;
    }
}

// ---------------------------------------------------------------------------
// K2: weights -> w8[tap][o][c] i8 sign + scaleW[o] = mean|w|.
// ---------------------------------------------------------------------------
__global__ __launch_bounds__(128) void pack_wgt8(const float* __restrict__ w,
                                                 char* __restrict__ w8,
                                                 float* __restrict__ scaleW) {
    __shared__ float red[128];
    int o = blockIdx.x, c = threadIdx.x;  // 128 threads = ch_in
    const float* wo = w + ((size_t)o * NCH + c) * 9;
    float s = 0.f;
#pragma unroll
    for (int t = 0; t < 9; ++t) {
        float v = wo[t];
        s += fabsf(v);
        w8[(size_t)t * NCH * NCH + (size_t)o * NCH + c] = (v > 0.f) ? 1 : -1;
    }
    red[c] = s;
    __syncthreads();
    for (int st = 64; st; st >>= 1) {
        if (c < st) red[c] += red[c + st];
        __syncthreads();
    }
    if (c == 0) scaleW[o] = red[0] / 1152.0f;
}

// ---------------------------------------------------------------------------
// Inner MFMA loop, specialized on per-subtile validity (no runtime branches
// in the 528 full-tile blocks).
// ---------------------------------------------------------------------------
template <bool V0, bool V1, bool V2>
__device__ __forceinline__ void conv_loop(const char* lds, const char* wlane, int hl,
                                          int pw0, int rb0, int pw1, int rb1,
                                          int pw2, int rb2,
                                          v16i& acc0, v16i& acc1, v16i& acc2) {
#pragma unroll
    for (int tap = 0; tap < 9; ++tap) {
        const int th = tap / 3, tw = tap - 3 * (tap / 3);
        const int trow = th * ROWB;
#pragma unroll
        for (int ks = 0; ks < 4; ++ks) {
            v4i a = *reinterpret_cast<const v4i*>(wlane + tap * (NCH * NCH) + ks * 32);
            int gq = ks * 2 + hl;
            if constexpr (V0) {
                int col = pw0 + tw;
                v4i b = *reinterpret_cast<const v4i*>(
                    lds + rb0 + trow + col * NCH + ((gq ^ (col & 7)) << 4));
                acc0 = __builtin_amdgcn_mfma_i32_32x32x32_i8(a, b, acc0, 0, 0, 0);
            }
            if constexpr (V1) {
                int col = pw1 + tw;
                v4i b = *reinterpret_cast<const v4i*>(
                    lds + rb1 + trow + col * NCH + ((gq ^ (col & 7)) << 4));
                acc1 = __builtin_amdgcn_mfma_i32_32x32x32_i8(a, b, acc1, 0, 0, 0);
            }
            if constexpr (V2) {
                int col = pw2 + tw;
                v4i b = *reinterpret_cast<const v4i*>(
                    lds + rb2 + trow + col * NCH + ((gq ^ (col & 7)) << 4));
                acc2 = __builtin_amdgcn_mfma_i32_32x32x32_i8(a, b, acc2, 0, 0, 0);
            }
        }
    }
}

// ---------------------------------------------------------------------------
// K3: binary conv as i8 MFMA GEMM. Block = 512 threads (8 waves); block covers
// (n, 192-pixel tile); wave (og, phh) = 32-ch_out group x 96-pixel half ->
// 3 independent 32x32 accumulator chains per wave (ILP-3). Grid 32*17 = 544.
// Act halo (7 padded rows) staged in LDS, granule-XOR swizzled. LDS 51.9KB ->
// 3 blocks/CU = 24 waves/CU. Zero-padding exact via i8 zeros.
// MODE 0: per-channel partial sum/sumsq. MODE 1: fused BN+residual+PReLU out.
// ---------------------------------------------------------------------------
template <int MODE>
__global__ __launch_bounds__(512, 4) void conv_mfma(
    const char* __restrict__ act8, const char* __restrict__ w8,
    int* __restrict__ sumP, int* __restrict__ sqP,
    const float* __restrict__ coefA, const float* __restrict__ coefB,
    const float* __restrict__ alpha, const float* __restrict__ bias2,
    const float* __restrict__ x, float* __restrict__ out) {
    __shared__ char lds[LROWS * ROWB];  // 51968 B

    int bid = blockIdx.x;
    int n = bid / NTILE, bt = bid - n * NTILE;
    int pbase = bt * TPX;
    int h0 = pbase / NW;

    // Stage 7 padded rows (h0..h0+6, clamped) with granule swizzle g^=col&7.
    const char* an = act8 + (size_t)n * IMG_BYTES;
    for (int j = threadIdx.x; j < LROWS * PADD * 8; j += 512) {
        int r = j / (PADD * 8);
        int rem2 = j - r * (PADD * 8);
        int col = rem2 >> 3, g = rem2 & 7;
        int rp = h0 + r;
        if (rp > PADD - 1) rp = PADD - 1;
        v4i v = *reinterpret_cast<const v4i*>(an + (size_t)rp * ROWB + col * NCH + g * 16);
        *reinterpret_cast<v4i*>(lds + r * ROWB + col * NCH + ((g ^ (col & 7)) << 4)) = v;
    }
    __syncthreads();

    int wid = threadIdx.x >> 6, lane = threadIdx.x & 63;
    int og = wid & 3, phh = wid >> 2;
    int l31 = lane & 31, hl = lane >> 5;
    int sbase = pbase + phh * 96;

    bool sv0 = (sbase + 31) < NHW_;
    bool sv1 = (sbase + 63) < NHW_;
    bool sv2 = (sbase + 95) < NHW_;

    int p0 = sbase + l31;      if (p0 > NHW_ - 1) p0 = NHW_ - 1;
    int p1 = sbase + 32 + l31; if (p1 > NHW_ - 1) p1 = NHW_ - 1;
    int p2 = sbase + 64 + l31; if (p2 > NHW_ - 1) p2 = NHW_ - 1;
    int ph0 = p0 / NW, pw0 = p0 - ph0 * NW, rb0 = (ph0 - h0) * ROWB;
    int ph1 = p1 / NW, pw1 = p1 - ph1 * NW, rb1 = (ph1 - h0) * ROWB;
    int ph2 = p2 / NW, pw2 = p2 - ph2 * NW, rb2 = (ph2 - h0) * ROWB;

    const char* wlane = w8 + (size_t)(og * 32 + l31) * NCH + hl * 16;

    v16i acc0 = {0}, acc1 = {0}, acc2 = {0};

    if (sv2)
        conv_loop<true, true, true>(lds, wlane, hl, pw0, rb0, pw1, rb1, pw2, rb2,
                                    acc0, acc1, acc2);
    else if (sv1)
        conv_loop<true, true, false>(lds, wlane, hl, pw0, rb0, pw1, rb1, pw2, rb2,
                                     acc0, acc1, acc2);
    else if (sv0)
        conv_loop<true, false, false>(lds, wlane, hl, pw0, rb0, pw1, rb1, pw2, rb2,
                                      acc0, acc1, acc2);

    // D layout (verified): col(pixel)=lane&31, row(ch)=(reg&3)+8*(reg>>2)+4*(lane>>5).
    if (MODE == 0) {
        int slot = (n * NTILE + bt) * 2 + phh;
#pragma unroll
        for (int r = 0; r < 16; ++r) {
            int d0 = acc0[r], d1 = acc1[r], d2 = acc2[r];  // invalid subtiles stay 0
            int s = d0 + d1 + d2;
            int q = __mul24(d0, d0) + __mul24(d1, d1) + __mul24(d2, d2);
            s = sum32(s);
            q = sum32(q);
            if (l31 == 31) {
                int ch = og * 32 + (r & 3) + 8 * (r >> 2) + 4 * hl;
                sumP[ch * NSLOT + slot] = s;
                sqP[ch * NSLOT + slot] = q;
            }
        }
    } else {
#pragma unroll
        for (int r = 0; r < 16; ++r) {
            int ch = og * 32 + (r & 3) + 8 * (r >> 2) + 4 * hl;
            float ca = coefA[ch], cb = coefB[ch], al = alpha[ch], b2 = bias2[ch];
            size_t base = ((size_t)n * NCH + ch) * NHW_ + sbase + l31;
            if (sv0) {
                float t = fmaf(ca, (float)acc0[r], cb) + x[base];
                t = t >= 0.f ? t : al * t;
                out[base] = t + b2;
            }
            if (sv1) {
                float t = fmaf(ca, (float)acc1[r], cb) + x[base + 32];
                t = t >= 0.f ? t : al * t;
                out[base + 32] = t + b2;
            }
            if (sv2) {
                float t = fmaf(ca, (float)acc2[r], cb) + x[base + 64];
                t = t >= 0.f ? t : al * t;
                out[base + 64] = t + b2;
            }
        }
    }
}

// ---------------------------------------------------------------------------
// K4: fold partial stats + scale + BN + bias1 into per-channel affine.
// 128 blocks x 64 threads; each block reduces 1088 partials for one channel.
// ---------------------------------------------------------------------------
__global__ __launch_bounds__(64) void bn_coef2(const int* __restrict__ sumP,
                                               const int* __restrict__ sqP,
                                               const float* __restrict__ scaleW,
                                               const float* __restrict__ gamma,
                                               const float* __restrict__ beta,
                                               const float* __restrict__ bias1,
                                               float* __restrict__ coefA,
                                               float* __restrict__ coefB) {
    int o = blockIdx.x;
    int t = threadIdx.x;
    long long s = 0, q = 0;
    for (int i = t; i < NSLOT; i += 64) {
        s += sumP[o * NSLOT + i];
        q += sqP[o * NSLOT + i];
    }
#pragma unroll
    for (int off = 32; off; off >>= 1) {
        s += __shfl_down(s, off);
        q += __shfl_down(q, off);
    }
    if (t == 0) {
        double cnt = (double)NPIX;
        double mean = (double)s / cnt;
        double var = (double)q / cnt - mean * mean;
        if (var < 0.0) var = 0.0;
        float sc = scaleW[o];
        float rs = rsqrtf((float)((double)sc * (double)sc * var) + 1e-5f);
        float g = gamma[o];
        coefA[o] = sc * g * rs;
        coefB[o] = beta[o] - (float)((double)sc * mean) * g * rs + bias1[o];
    }
}

// ---------------------------------------------------------------------------
// Workspace layout (bytes):
//   0          act8   (32*58*58*128 i8)  13,778,944
//   13778944   w8     (9*128*128 i8)        147,456
//   13926400   scaleW (128 f32)                 512
//   13926912   coefA  (128 f32)                 512
//   13927424   coefB  (128 f32)                 512
//   13927936   sumP   (128*1088 i32)         557,056
//   14484992   sqP    (128*1088 i32)         557,056  -> total 15,042,048
// ---------------------------------------------------------------------------
extern "C" void kernel_launch(void* const* d_in, const int* in_sizes, int n_in,
                              void* d_out, int out_size, void* d_ws, size_t ws_size,
                              hipStream_t stream) {
    (void)in_sizes; (void)n_in; (void)out_size; (void)ws_size;
    const float* x     = (const float*)d_in[0];
    const float* bias0 = (const float*)d_in[1];
    const float* w     = (const float*)d_in[2];
    const float* gamma = (const float*)d_in[3];
    const float* beta  = (const float*)d_in[4];
    const float* bias1 = (const float*)d_in[5];
    const float* alpha = (const float*)d_in[6];
    const float* bias2 = (const float*)d_in[7];
    float* out = (float*)d_out;
    char* ws = (char*)d_ws;

    char*  act8   = ws;
    char*  w8     = ws + 13778944;
    float* scaleW = (float*)(ws + 13926400);
    float* coefA  = (float*)(ws + 13926912);
    float* coefB  = (float*)(ws + 13927424);
    int*   sumP   = (int*)(ws + 13927936);
    int*   sqP    = (int*)(ws + 14484992);

    pack_act8<<<(NB * PADD * PADD + 255) / 256, 256, 0, stream>>>(x, bias0, act8);
    pack_wgt8<<<NCH, 128, 0, stream>>>(w, w8, scaleW);

    conv_mfma<0><<<NB * NTILE, 512, 0, stream>>>(
        act8, w8, sumP, sqP, nullptr, nullptr, nullptr, nullptr, nullptr, nullptr);
    bn_coef2<<<NCH, 64, 0, stream>>>(sumP, sqP, scaleW, gamma, beta, bias1, coefA, coefB);
    conv_mfma<1><<<NB * NTILE, 512, 0, stream>>>(
        act8, w8, sumP, sqP, coefA, coefB, alpha, bias2, x, out);
}

// Round 12
// 113.732 us; speedup vs baseline: 1.1277x; 1.1277x over previous
//
#include <hip/hip_runtime.h>
#include <stdint.h>

// Problem constants (fixed by setup_inputs)
#define NB 32
#define NCH 128
#define NH 56
#define NW 56
#define NHW_ 3136
#define NPIX 100352
#define PADD 58                               // padded spatial dim (h,w in [-1,56])
#define IMG_BYTES ((size_t)PADD * PADD * NCH)   // 430592
#define TILES 13                              // 256-px tiles per image (last = 64px)
#define TPX 256
#define NSLOT (NB * TILES * 4)                // 1664 stat slots per channel
#define ROWB (PADD * NCH)                     // 7424 B per padded row

typedef int v4i __attribute__((ext_vector_type(4)));
typedef int v16i __attribute__((ext_vector_type(16)));

// ---------------------------------------------------------------------------
// 32-lane-half sum via DPP (VALU pipe). lane31 = sum(0..31), lane63 = sum(32..63).
// ---------------------------------------------------------------------------
__device__ __forceinline__ int sum32(int v) {
    v += __builtin_amdgcn_update_dpp(0, v, 0x111, 0xF, 0xF, true);  // row_shr:1
    v += __builtin_amdgcn_update_dpp(0, v, 0x112, 0xF, 0xF, true);  // row_shr:2
    v += __builtin_amdgcn_update_dpp(0, v, 0x114, 0xF, 0xF, true);  // row_shr:4
    v += __builtin_amdgcn_update_dpp(0, v, 0x118, 0xF, 0xF, true);  // row_shr:8
    v += __builtin_amdgcn_update_dpp(0, v, 0x142, 0xF, 0xF, true);  // row_bcast:15
    return v;
}

// ---------------------------------------------------------------------------
// K1: x (NCHW f32) -> act8 (padded NHWC i8 sign +1/-1). Grid covers the FULL
// padded grid; border threads write zeros (no separate memset).
// ---------------------------------------------------------------------------
__global__ __launch_bounds__(256) void pack_act8(const float* __restrict__ x,
                                                 const float* __restrict__ bias0,
                                                 char* __restrict__ act8) {
    int q = blockIdx.x * 256 + threadIdx.x;
    if (q >= NB * PADD * PADD) return;
    int n = q / (PADD * PADD);
    int rem = q - n * (PADD * PADD);
    int hp = rem / PADD, wp = rem - (rem / PADD) * PADD;
    char* dst = act8 + (size_t)n * IMG_BYTES + (size_t)rem * NCH;
    if (hp == 0 || hp == PADD - 1 || wp == 0 || wp == PADD - 1) {
        v4i z = {0, 0, 0, 0};
#pragma unroll
        for (int g = 0; g < 8; ++g) *reinterpret_cast<v4i*>(dst + g * 16) = z;
        return;
    }
    int pix = (hp - 1) * NW + (wp - 1);
    const float* xb = x + (size_t)n * NCH * NHW_ + pix;
#pragma unroll
    for (int g = 0; g < 8; ++g) {
        int d[4];
#pragma unroll
        for (int dw = 0; dw < 4; ++dw) {
            unsigned v = 0;
#pragma unroll
            for (int b = 0; b < 4; ++b) {
                int c = g * 16 + dw * 4 + b;
                bool pos = (xb[(size_t)c * NHW_] + bias0[c]) > 0.f;
                v |= (unsigned)(pos ? 0x01u : 0xFFu) << (8 * b);
            }
            d[dw] = (int)v;
        }
        v4i qv = {d[0], d[1], d[2], d[3]};
        *reinterpret_cast<v4i*>(dst + g * 16) = qv;
    }
}

// ---------------------------------------------------------------------------
// K2: weights -> w8[tap][o][c] i8 sign + scaleW[o] = mean|w|.
// ---------------------------------------------------------------------------
__global__ __launch_bounds__(128) void pack_wgt8(const float* __restrict__ w,
                                                 char* __restrict__ w8,
                                                 float* __restrict__ scaleW) {
    __shared__ float red[128];
    int o = blockIdx.x, c = threadIdx.x;  // 128 threads = ch_in
    const float* wo = w + ((size_t)o * NCH + c) * 9;
    float s = 0.f;
#pragma unroll
    for (int t = 0; t < 9; ++t) {
        float v = wo[t];
        s += fabsf(v);
        w8[(size_t)t * NCH * NCH + (size_t)o * NCH + c] = (v > 0.f) ? 1 : -1;
    }
    red[c] = s;
    __syncthreads();
    for (int st = 64; st; st >>= 1) {
        if (c < st) red[c] += red[c + st];
        __syncthreads();
    }
    if (c == 0) scaleW[o] = red[0] / 1152.0f;
}

// ---------------------------------------------------------------------------
// K3: binary conv as i8 MFMA GEMM, BOTH operands from LDS.
// Block = 512 thr (8 waves = 2 og-groups x 4 pixel-groups); block covers
// (ch-half cb: 64 out-ch, n, 256-px tile). Grid 2*32*13 = 832.
// LDS: weight slab 9*64*128 = 73728 B + act slab 8 rows = 59392 B -> 133 KB,
// 1 block/CU, 2 waves/SIMD, both slabs granule-XOR swizzled (<=4-way).
// Per wave: ILP-2 (2x 32-px subtiles), 72 MFMA, 36 a-reads + 72 b-reads (ds).
// 3136 = 49*64 -> subtile validity is wave-uniform (no partial tails).
// MODE 0: per-channel partial sum/sumsq. MODE 1: fused BN+residual+PReLU out.
// ---------------------------------------------------------------------------
template <int MODE>
__global__ __launch_bounds__(512, 2) void conv_mfma(
    const char* __restrict__ act8, const char* __restrict__ w8,
    int* __restrict__ sumP, int* __restrict__ sqP,
    const float* __restrict__ coefA, const float* __restrict__ coefB,
    const float* __restrict__ alpha, const float* __restrict__ bias2,
    const float* __restrict__ x, float* __restrict__ out) {
    __shared__ char wslab[9 * 64 * NCH];  // 73728 B
    __shared__ char aslab[8 * ROWB];      // 59392 B

    int bid = blockIdx.x;                  // cb*(NB*TILES) + n*TILES + bt
    int cb = bid / (NB * TILES);
    int rem = bid - cb * (NB * TILES);
    int n = rem / TILES, bt = rem - (rem / TILES) * TILES;
    int pbase = bt * TPX;
    int h0 = pbase / NW;

    // Stage weight slab (this block's 64 out-channels), swizzle g ^= ch&7.
    {
        const char* wsrc = w8 + (size_t)cb * 64 * NCH;
        for (int j = threadIdx.x; j < 9 * 64 * 8; j += 512) {
            int tap = j >> 9;
            int r2 = j & 511;
            int chl = r2 >> 3, g = r2 & 7;
            v4i v = *reinterpret_cast<const v4i*>(
                wsrc + (size_t)tap * NCH * NCH + chl * NCH + g * 16);
            *reinterpret_cast<v4i*>(wslab + tap * 8192 + chl * NCH +
                                    ((g ^ (chl & 7)) << 4)) = v;
        }
    }
    // Stage 8 padded act rows (h0..h0+7, clamped), swizzle g ^= col&7.
    {
        const char* an = act8 + (size_t)n * IMG_BYTES;
        for (int j = threadIdx.x; j < 8 * PADD * 8; j += 512) {
            int r = j / (PADD * 8);
            int r2 = j - r * (PADD * 8);
            int col = r2 >> 3, g = r2 & 7;
            int rp = h0 + r;
            if (rp > PADD - 1) rp = PADD - 1;
            v4i v = *reinterpret_cast<const v4i*>(an + (size_t)rp * ROWB + col * NCH + g * 16);
            *reinterpret_cast<v4i*>(aslab + r * ROWB + col * NCH +
                                    ((g ^ (col & 7)) << 4)) = v;
        }
    }
    __syncthreads();

    int wid = threadIdx.x >> 6, lane = threadIdx.x & 63;
    int og = wid & 1, pxg = wid >> 1;
    int l31 = lane & 31, hl = lane >> 5;
    int sbase = pbase + pxg * 64;
    bool valid = sbase < NHW_;  // 64-aligned subtiles: all-or-nothing per wave

    int ch_l = og * 32 + l31;
    const char* wl = wslab + ch_l * NCH;
    int wswz = ch_l & 7;

    v16i acc0 = {0}, acc1 = {0};

    int p0 = sbase + l31, p1 = sbase + 32 + l31;
    if (!valid) { p0 = 0; p1 = 0; }
    int ph0 = p0 / NW, pw0 = p0 - ph0 * NW;
    int ph1 = p1 / NW, pw1 = p1 - ph1 * NW;
    int ab0 = (ph0 - h0) * ROWB;
    int ab1 = (ph1 - h0) * ROWB;

    if (valid) {
#pragma unroll
        for (int tap = 0; tap < 9; ++tap) {
            const int th = tap / 3, tw = tap - 3 * (tap / 3);
            int c0 = pw0 + tw, c1 = pw1 + tw;
            int b0b = ab0 + th * ROWB + c0 * NCH;
            int b1b = ab1 + th * ROWB + c1 * NCH;
            int s0 = c0 & 7, s1 = c1 & 7;
#pragma unroll
            for (int ks = 0; ks < 4; ++ks) {
                int g = ks * 2 + hl;
                v4i a = *reinterpret_cast<const v4i*>(wl + tap * 8192 + ((g ^ wswz) << 4));
                v4i b0 = *reinterpret_cast<const v4i*>(aslab + b0b + ((g ^ s0) << 4));
                acc0 = __builtin_amdgcn_mfma_i32_32x32x32_i8(a, b0, acc0, 0, 0, 0);
                v4i b1 = *reinterpret_cast<const v4i*>(aslab + b1b + ((g ^ s1) << 4));
                acc1 = __builtin_amdgcn_mfma_i32_32x32x32_i8(a, b1, acc1, 0, 0, 0);
            }
        }
    }

    // D layout (verified): col(pixel)=lane&31, row(ch)=(reg&3)+8*(reg>>2)+4*(lane>>5).
    if (MODE == 0) {
        int slot = (n * TILES + bt) * 4 + pxg;
#pragma unroll
        for (int r = 0; r < 16; ++r) {
            int d0 = acc0[r], d1 = acc1[r];
            int s = sum32(d0 + d1);
            int q = sum32(d0 * d0 + d1 * d1);
            if (l31 == 31) {
                int ch = cb * 64 + og * 32 + (r & 3) + 8 * (r >> 2) + 4 * hl;
                sumP[ch * NSLOT + slot] = s;
                sqP[ch * NSLOT + slot] = q;
            }
        }
    } else if (valid) {
#pragma unroll
        for (int r = 0; r < 16; ++r) {
            int ch = cb * 64 + og * 32 + (r & 3) + 8 * (r >> 2) + 4 * hl;
            float ca = coefA[ch], cbf = coefB[ch], al = alpha[ch], b2 = bias2[ch];
            size_t base = ((size_t)n * NCH + ch) * NHW_ + sbase + l31;
            float t0 = fmaf(ca, (float)acc0[r], cbf) + x[base];
            t0 = t0 >= 0.f ? t0 : al * t0;
            out[base] = t0 + b2;
            float t1 = fmaf(ca, (float)acc1[r], cbf) + x[base + 32];
            t1 = t1 >= 0.f ? t1 : al * t1;
            out[base + 32] = t1 + b2;
        }
    }
}

// ---------------------------------------------------------------------------
// K4: fold partial stats + scale + BN + bias1 into per-channel affine.
// 128 blocks x 64 threads; each block reduces 1664 partials for one channel.
// ---------------------------------------------------------------------------
__global__ __launch_bounds__(64) void bn_coef2(const int* __restrict__ sumP,
                                               const int* __restrict__ sqP,
                                               const float* __restrict__ scaleW,
                                               const float* __restrict__ gamma,
                                               const float* __restrict__ beta,
                                               const float* __restrict__ bias1,
                                               float* __restrict__ coefA,
                                               float* __restrict__ coefB) {
    int o = blockIdx.x;
    int t = threadIdx.x;
    long long s = 0, q = 0;
    for (int i = t; i < NSLOT; i += 64) {
        s += sumP[o * NSLOT + i];
        q += sqP[o * NSLOT + i];
    }
#pragma unroll
    for (int off = 32; off; off >>= 1) {
        s += __shfl_down(s, off);
        q += __shfl_down(q, off);
    }
    if (t == 0) {
        double cnt = (double)NPIX;
        double mean = (double)s / cnt;
        double var = (double)q / cnt - mean * mean;
        if (var < 0.0) var = 0.0;
        float sc = scaleW[o];
        float rs = rsqrtf((float)((double)sc * (double)sc * var) + 1e-5f);
        float g = gamma[o];
        coefA[o] = sc * g * rs;
        coefB[o] = beta[o] - (float)((double)sc * mean) * g * rs + bias1[o];
    }
}

// ---------------------------------------------------------------------------
// Workspace layout (bytes):
//   0          act8   (32*58*58*128 i8)  13,778,944
//   13778944   w8     (9*128*128 i8)        147,456
//   13926400   scaleW (128 f32)                 512
//   13926912   coefA  (128 f32)                 512
//   13927424   coefB  (128 f32)                 512
//   13927936   sumP   (128*1664 i32)         851,968
//   14779904   sqP    (128*1664 i32)         851,968  -> total 15,631,872
// ---------------------------------------------------------------------------
extern "C" void kernel_launch(void* const* d_in, const int* in_sizes, int n_in,
                              void* d_out, int out_size, void* d_ws, size_t ws_size,
                              hipStream_t stream) {
    (void)in_sizes; (void)n_in; (void)out_size; (void)ws_size;
    const float* x     = (const float*)d_in[0];
    const float* bias0 = (const float*)d_in[1];
    const float* w     = (const float*)d_in[2];
    const float* gamma = (const float*)d_in[3];
    const float* beta  = (const float*)d_in[4];
    const float* bias1 = (const float*)d_in[5];
    const float* alpha = (const float*)d_in[6];
    const float* bias2 = (const float*)d_in[7];
    float* out = (float*)d_out;
    char* ws = (char*)d_ws;

    char*  act8   = ws;
    char*  w8     = ws + 13778944;
    float* scaleW = (float*)(ws + 13926400);
    float* coefA  = (float*)(ws + 13926912);
    float* coefB  = (float*)(ws + 13927424);
    int*   sumP   = (int*)(ws + 13927936);
    int*   sqP    = (int*)(ws + 14779904);

    pack_act8<<<(NB * PADD * PADD + 255) / 256, 256, 0, stream>>>(x, bias0, act8);
    pack_wgt8<<<NCH, 128, 0, stream>>>(w, w8, scaleW);

    conv_mfma<0><<<2 * NB * TILES, 512, 0, stream>>>(
        act8, w8, sumP, sqP, nullptr, nullptr, nullptr, nullptr, nullptr, nullptr);
    bn_coef2<<<NCH, 64, 0, stream>>>(sumP, sqP, scaleW, gamma, beta, bias1, coefA, coefB);
    conv_mfma<1><<<2 * NB * TILES, 512, 0, stream>>>(
        act8, w8, sumP, sqP, coefA, coefB, alpha, bias2, x, out);
}